// Round 6
// baseline (563.709 us; speedup 1.0000x reference)
//
#include <hip/hip_runtime.h>
#include <hip/hip_bf16.h>
#include <stddef.h>

// GCN link predictor: 3x (GCNConv -> BN -> [sigmoid]) then edge dot decode.
//  - CSR by dst via 2-level binned counting sort (write-coalesced, packed pairs).
//  - bf16 activations; MFMA 16x16x32 GEMMs: whole-K A panel staged once in LDS
//    (XOR chunk swizzle), then a barrier-free K-loop with B prefetched 1 slice ahead.
//  - BN apply+sigmoid fused into GEMM A-staging; BN finalize folded into consumers.
//  - BN stats fused in GEMM1 epilogue; streaming pass after agg2/agg3.
//  - Agg: one-shot waves, 4-8 nodes/wave, 4-edge unrolled uint4 gathers (MLP).
//  - Biases cancel under training-mode BN -> skipped.  Assumes N <= 131072.

#define WAVE 64
#define BSHIFT 9                    // 512 nodes per coarse bucket
#define SCHUNK 4096                 // edges per bscatter block

typedef __attribute__((ext_vector_type(8))) short short8;
typedef __attribute__((ext_vector_type(4))) float f32x4;

__device__ __forceinline__ float bl(uint g) { return __uint_as_float(g << 16); }
__device__ __forceinline__ float bh(uint g) { return __uint_as_float(g & 0xffff0000u); }
__device__ __forceinline__ ushort f2b(float f) {           // round-to-nearest-even
    uint u = __float_as_uint(f);
    return (ushort)((u + 0x7fffu + ((u >> 16) & 1u)) >> 16);
}
__device__ __forceinline__ uint pack2(float lo, float hi) {
    return (uint)f2b(lo) | ((uint)f2b(hi) << 16);
}

// ================= binned counting sort (CSR build) =================
__global__ __launch_bounds__(256) void k_bhist(const int* __restrict__ dst, int* __restrict__ gh, int E) {
    __shared__ int lh[256];
    lh[threadIdx.x] = 0; __syncthreads();
    int i = blockIdx.x * 256 + threadIdx.x, stride = gridDim.x * 256;
    for (; i < E; i += stride) atomicAdd(&lh[dst[i] >> BSHIFT], 1);
    __syncthreads();
    int v = lh[threadIdx.x];
    if (v) atomicAdd(&gh[threadIdx.x], v);
}

__global__ void k_bscan(const int* __restrict__ gh, int* __restrict__ boff, int* __restrict__ bcur) {
    __shared__ int ls[256];
    int t = threadIdx.x;
    int v = gh[t];
    ls[t] = v; __syncthreads();
    for (int off = 1; off < 256; off <<= 1) {
        int x = (t >= off) ? ls[t - off] : 0;
        __syncthreads();
        ls[t] += x;
        __syncthreads();
    }
    int excl = ls[t] - v;
    boff[t] = excl; bcur[t] = excl;
    if (t == 255) boff[256] = ls[255];
}

// pairs packed: (dst & 511) << 17 | src   (src < 2^17, dloc < 2^9)
__global__ __launch_bounds__(256) void k_bscatter(const int* __restrict__ src, const int* __restrict__ dst,
                                                  int* __restrict__ gcur, uint* __restrict__ pairs, int E) {
    __shared__ int lh[256];
    int t = threadIdx.x;
    int base = blockIdx.x * SCHUNK;
    lh[t] = 0; __syncthreads();
    int rs[16], rd[16];
    #pragma unroll
    for (int i = 0; i < 16; ++i) {
        int idx = base + i * 256 + t;
        if (idx < E) { rs[i] = src[idx]; rd[i] = dst[idx]; atomicAdd(&lh[rd[i] >> BSHIFT], 1); }
        else rd[i] = -1;
    }
    __syncthreads();
    int cnt_b = lh[t];
    int b0 = cnt_b ? atomicAdd(&gcur[t], cnt_b) : 0;
    lh[t] = b0;
    __syncthreads();
    #pragma unroll
    for (int i = 0; i < 16; ++i) {
        if (rd[i] >= 0) {
            int p = atomicAdd(&lh[rd[i] >> BSHIFT], 1);
            pairs[p] = ((uint)(rd[i] & 511) << 17) | (uint)rs[i];
        }
    }
}

// per-bucket: fine counting sort; also emits rowptr + dinv
__global__ __launch_bounds__(256) void k_bfine(const uint* __restrict__ pairs, const int* __restrict__ boff,
                                               int* __restrict__ rowptr, int* __restrict__ srcs,
                                               float* __restrict__ dinv, int N, int E) {
    __shared__ int lcnt[512];
    __shared__ int ls[256];
    int b = blockIdx.x, t = threadIdx.x;
    int d0 = b << BSHIFT;
    int e0 = boff[b], e1 = boff[b + 1];
    lcnt[t] = 0; lcnt[t + 256] = 0;
    __syncthreads();
    for (int e = e0 + t; e < e1; e += 256)
        atomicAdd(&lcnt[pairs[e] >> 17], 1);
    __syncthreads();
    int c0 = lcnt[2 * t], c1 = lcnt[2 * t + 1];
    ls[t] = c0 + c1;
    __syncthreads();
    for (int off = 1; off < 256; off <<= 1) {
        int x = (t >= off) ? ls[t - off] : 0;
        __syncthreads();
        ls[t] += x;
        __syncthreads();
    }
    int excl = ls[t] - (c0 + c1);
    int s0 = excl, s1 = excl + c0;
    int d = d0 + 2 * t;
    if (d < N)     { rowptr[d] = e0 + s0;     dinv[d] = rsqrtf((float)(c0 + 1)); }
    if (d + 1 < N) { rowptr[d + 1] = e0 + s1; dinv[d + 1] = rsqrtf((float)(c1 + 1)); }
    if (b == 0 && t == 0) rowptr[N] = E;
    lcnt[2 * t] = s0; lcnt[2 * t + 1] = s1;
    __syncthreads();
    for (int e = e0 + t; e < e1; e += 256) {
        uint p = pairs[e];
        int pos = atomicAdd(&lcnt[p >> 17], 1);
        srcs[e0 + pos] = (int)(p & 0x1FFFFu);
    }
}

// ================= conversions =================
__global__ void k_convx(const float* __restrict__ in, ushort* __restrict__ out, size_t n4) {
    size_t i = (size_t)blockIdx.x * blockDim.x + threadIdx.x;
    if (i >= n4) return;
    float4 v = reinterpret_cast<const float4*>(in)[i];
    uint2 o;
    o.x = pack2(v.x, v.y);
    o.y = pack2(v.z, v.w);
    reinterpret_cast<uint2*>(out)[i] = o;
}

// all three weights transposed+converted in one launch: Wt[n*K+k] = bf16(W[k*N+n])
__global__ void k_convW(const float* __restrict__ W1, const float* __restrict__ W2,
                        const float* __restrict__ W3, ushort* __restrict__ Wt1,
                        ushort* __restrict__ Wt2, ushort* __restrict__ Wt3) {
    int i = blockIdx.x * blockDim.x + threadIdx.x;
    const float* W; ushort* Wt; int K, Nn, j;
    if (i < 32768)      { W = W1; Wt = Wt1; K = 128; Nn = 256; j = i; }
    else if (i < 65536) { W = W2; Wt = Wt2; K = 256; Nn = 128; j = i - 32768; }
    else if (i < 73728) { W = W3; Wt = Wt3; K = 128; Nn = 64;  j = i - 65536; }
    else return;
    int k = j / Nn, n = j % Nn;
    Wt[(size_t)n * K + k] = f2b(W[k * Nn + n]);
}

// ================= aggregation: out[i] = dinv[i]*( sum_e dinv[s]*in[s] + dinv[i]*in[i] ) =================
template<int F>
__global__ __launch_bounds__(256) void k_agg(const ushort* __restrict__ in, ushort* __restrict__ out,
                                             const int* __restrict__ rowptr, const int* __restrict__ srcs,
                                             const float* __restrict__ dinv, int N) {
    constexpr int L = (F * 2) / 16;          // lanes per node (uint4 = 16B each)
    int wv = threadIdx.x >> 6, lane = threadIdx.x & 63;
    int node = (blockIdx.x * 4 + wv) * (64 / L) + lane / L;
    int sl = lane % L;
    if (node >= N) return;
    const uint4* inq = reinterpret_cast<const uint4*>(in);
    float di = dinv[node];
    float acc[8];
    {
        uint4 v = inq[(size_t)node * L + sl];
        acc[0] = di * bl(v.x); acc[1] = di * bh(v.x);
        acc[2] = di * bl(v.y); acc[3] = di * bh(v.y);
        acc[4] = di * bl(v.z); acc[5] = di * bh(v.z);
        acc[6] = di * bl(v.w); acc[7] = di * bh(v.w);
    }
    int e = rowptr[node], e1 = rowptr[node + 1];
    for (; e + 3 < e1; e += 4) {
        int s0 = srcs[e], s1 = srcs[e + 1], s2 = srcs[e + 2], s3 = srcs[e + 3];
        float d0 = dinv[s0], d1 = dinv[s1], d2 = dinv[s2], d3 = dinv[s3];
        uint4 v0 = inq[(size_t)s0 * L + sl];
        uint4 v1 = inq[(size_t)s1 * L + sl];
        uint4 v2 = inq[(size_t)s2 * L + sl];
        uint4 v3 = inq[(size_t)s3 * L + sl];
        acc[0] += d0 * bl(v0.x) + d1 * bl(v1.x) + d2 * bl(v2.x) + d3 * bl(v3.x);
        acc[1] += d0 * bh(v0.x) + d1 * bh(v1.x) + d2 * bh(v2.x) + d3 * bh(v3.x);
        acc[2] += d0 * bl(v0.y) + d1 * bl(v1.y) + d2 * bl(v2.y) + d3 * bl(v3.y);
        acc[3] += d0 * bh(v0.y) + d1 * bh(v1.y) + d2 * bh(v2.y) + d3 * bh(v3.y);
        acc[4] += d0 * bl(v0.z) + d1 * bl(v1.z) + d2 * bl(v2.z) + d3 * bl(v3.z);
        acc[5] += d0 * bh(v0.z) + d1 * bh(v1.z) + d2 * bh(v2.z) + d3 * bh(v3.z);
        acc[6] += d0 * bl(v0.w) + d1 * bl(v1.w) + d2 * bl(v2.w) + d3 * bl(v3.w);
        acc[7] += d0 * bh(v0.w) + d1 * bh(v1.w) + d2 * bh(v2.w) + d3 * bh(v3.w);
    }
    for (; e < e1; ++e) {
        int s0 = srcs[e];
        float d0 = dinv[s0];
        uint4 v0 = inq[(size_t)s0 * L + sl];
        acc[0] += d0 * bl(v0.x); acc[1] += d0 * bh(v0.x);
        acc[2] += d0 * bl(v0.y); acc[3] += d0 * bh(v0.y);
        acc[4] += d0 * bl(v0.z); acc[5] += d0 * bh(v0.z);
        acc[6] += d0 * bl(v0.w); acc[7] += d0 * bh(v0.w);
    }
    uint4 o;
    o.x = pack2(acc[0] * di, acc[1] * di);
    o.y = pack2(acc[2] * di, acc[3] * di);
    o.z = pack2(acc[4] * di, acc[5] * di);
    o.w = pack2(acc[6] * di, acc[7] * di);
    reinterpret_cast<uint4*>(out)[(size_t)node * L + sl] = o;
}

// ================= vectorized BN stats (streaming, bf16 uint4 loads) =================
template<int F>
__global__ __launch_bounds__(256) void k_bnstats(const ushort* __restrict__ h, float* __restrict__ gsum,
                                                 float* __restrict__ gsq, int N) {
    constexpr int C = F / 8;                 // uint4 chunks per row (16 or 8)
    constexpr int RPW = 64 / C;              // rows per wave per step
    __shared__ float ls[4][16][16];          // [wave][chunk][0..7 sum, 8..15 sq]
    int wv = threadIdx.x >> 6, lane = threadIdx.x & 63;
    int fidx = lane % C, rsub = lane / C;
    int row = (blockIdx.x * 4 + wv) * RPW + rsub;
    int rstride = gridDim.x * 4 * RPW;
    const uint4* hq = reinterpret_cast<const uint4*>(h);
    float s[8] = {}, q[8] = {};
    for (int r = row; r < N; r += rstride) {
        uint4 v = hq[(size_t)r * C + fidx];
        float x;
        x = bl(v.x); s[0] += x; q[0] += x * x;
        x = bh(v.x); s[1] += x; q[1] += x * x;
        x = bl(v.y); s[2] += x; q[2] += x * x;
        x = bh(v.y); s[3] += x; q[3] += x * x;
        x = bl(v.z); s[4] += x; q[4] += x * x;
        x = bh(v.z); s[5] += x; q[5] += x * x;
        x = bl(v.w); s[6] += x; q[6] += x * x;
        x = bh(v.w); s[7] += x; q[7] += x * x;
    }
    #pragma unroll
    for (int m = C; m < 64; m <<= 1) {
        #pragma unroll
        for (int j = 0; j < 8; ++j) { s[j] += __shfl_xor(s[j], m); q[j] += __shfl_xor(q[j], m); }
    }
    if (lane < C) {
        #pragma unroll
        for (int j = 0; j < 8; ++j) { ls[wv][lane][j] = s[j]; ls[wv][lane][8 + j] = q[j]; }
    }
    __syncthreads();
    int t = threadIdx.x;
    if (t < F) {
        int ch = t / 8, j = t % 8;
        float S = 0.f, Q = 0.f;
        #pragma unroll
        for (int w = 0; w < 4; ++w) { S += ls[w][ch][j]; Q += ls[w][ch][8 + j]; }
        atomicAdd(&gsum[t], S); atomicAdd(&gsq[t], Q);
    }
}

// ================= MFMA bf16 GEMM: C[M, NPASS*NF*32] = f(A)[M,K] @ Wt^T =================
// Whole-K A panel staged once into LDS (XOR chunk swizzle), then barrier-free K-loop
// with B fragments prefetched one 32-slice ahead. 4 waves (2x2); wave tile 64 x NF*16.
// APPLY: f = sigmoid(a*scale+shift), scale/shift computed in-kernel from raw BN sums.
// STATS: per-column sum/sumsq atomically accumulated for the NEXT layer's BN.
template<int K, int NF, int NPASS, bool APPLY, bool STATS>
__global__ __launch_bounds__(256) void k_mfma(const ushort* __restrict__ A, const ushort* __restrict__ Wt,
                                              ushort* __restrict__ C, int M, int Nout,
                                              const float* __restrict__ bsum, const float* __restrict__ bsq,
                                              const float* __restrict__ bg, const float* __restrict__ bb,
                                              float invN,
                                              float* __restrict__ gsum, float* __restrict__ gsq) {
    constexpr int CH = K / 8;                 // 16B chunks per row
    constexpr int KS = K / 32;                // 32-wide K slices
    __shared__ uint4 Alds[128 * CH];          // 32 KB (K=128) / 64 KB (K=256)
    __shared__ float scl[APPLY ? K : 1], shl[APPLY ? K : 1];
    int m0 = blockIdx.x * 128;
    int t = threadIdx.x;
    int w = t >> 6, lane = t & 63;
    int wr = w >> 1, wc = w & 1;
    int rf = lane & 15, kg = lane >> 4;

    if constexpr (APPLY) {
        for (int i = t; i < K; i += 256) {
            float m = bsum[i] * invN;
            float var = bsq[i] * invN - m * m;
            float sc = bg[i] * rsqrtf(var + 1e-5f);
            scl[i] = sc; shl[i] = bb[i] - m * sc;
        }
        __syncthreads();
    }

    // ---- stage whole A panel: global -> reg -> (transform) -> LDS ----
    #pragma unroll
    for (int i = 0; i < CH / 2; ++i) {
        int chunk = i * 256 + t;
        int r = chunk / CH, c = chunk % CH;
        int gr = m0 + r; if (gr >= M) gr = M - 1;        // clamp; store/stats guarded
        uint4 v = *reinterpret_cast<const uint4*>(A + (size_t)gr * K + c * 8);
        if constexpr (APPLY) {
            uint u[4] = {v.x, v.y, v.z, v.w};
            int kb = c * 8;
            #pragma unroll
            for (int j = 0; j < 4; ++j) {
                int k = kb + 2 * j;
                float x0 = bl(u[j]) * scl[k] + shl[k];
                float x1 = bh(u[j]) * scl[k + 1] + shl[k + 1];
                x0 = 1.f / (1.f + __expf(-x0));
                x1 = 1.f / (1.f + __expf(-x1));
                u[j] = pack2(x0, x1);
            }
            v.x = u[0]; v.y = u[1]; v.z = u[2]; v.w = u[3];
        }
        Alds[r * CH + (c ^ (r & 7))] = v;
    }
    __syncthreads();                                      // the only barrier before epilogue

    for (int pass = 0; pass < NPASS; ++pass) {
        int n0 = pass * NF * 32;
        const ushort* bp[NF];
        #pragma unroll
        for (int nf = 0; nf < NF; ++nf)
            bp[nf] = Wt + (size_t)(n0 + wc * (NF * 16) + nf * 16 + rf) * K + kg * 8;

        f32x4 acc[4][NF];
        #pragma unroll
        for (int mf = 0; mf < 4; ++mf)
            #pragma unroll
            for (int nf = 0; nf < NF; ++nf)
                acc[mf][nf] = (f32x4){0.f, 0.f, 0.f, 0.f};

        short8 bcur[NF];
        #pragma unroll
        for (int nf = 0; nf < NF; ++nf)
            bcur[nf] = *reinterpret_cast<const short8*>(bp[nf]);

        for (int ks = 0; ks < KS; ++ks) {
            short8 bnxt[NF];
            if (ks + 1 < KS) {
                #pragma unroll
                for (int nf = 0; nf < NF; ++nf)
                    bnxt[nf] = *reinterpret_cast<const short8*>(bp[nf] + (ks + 1) * 32);
            } else {
                #pragma unroll
                for (int nf = 0; nf < NF; ++nf) bnxt[nf] = bcur[nf];
            }
            short8 a[4];
            #pragma unroll
            for (int mf = 0; mf < 4; ++mf) {
                int R = wr * 64 + mf * 16 + rf;
                int c = ks * 4 + kg;
                a[mf] = *reinterpret_cast<const short8*>(&Alds[R * CH + (c ^ (R & 7))]);
            }
            #pragma unroll
            for (int mf = 0; mf < 4; ++mf)
                #pragma unroll
                for (int nf = 0; nf < NF; ++nf)
                    acc[mf][nf] = __builtin_amdgcn_mfma_f32_16x16x32_bf16(a[mf], bcur[nf], acc[mf][nf], 0, 0, 0);
            #pragma unroll
            for (int nf = 0; nf < NF; ++nf) bcur[nf] = bnxt[nf];
        }

        #pragma unroll
        for (int mf = 0; mf < 4; ++mf)
            #pragma unroll
            for (int nf = 0; nf < NF; ++nf) {
                int col = n0 + wc * (NF * 16) + nf * 16 + rf;
                #pragma unroll
                for (int j = 0; j < 4; ++j) {
                    int row = m0 + wr * 64 + mf * 16 + kg * 4 + j;
                    if (row < M) C[(size_t)row * Nout + col] = f2b(acc[mf][nf][j]);
                }
            }

        if constexpr (STATS) {
            __shared__ float bns[2][NF * 32], bnq[2][NF * 32];
            __syncthreads();                    // protect bns reuse across passes
            #pragma unroll
            for (int nf = 0; nf < NF; ++nf) {
                float cs = 0.f, cq = 0.f;
                #pragma unroll
                for (int mf = 0; mf < 4; ++mf)
                    #pragma unroll
                    for (int j = 0; j < 4; ++j) {
                        int row = m0 + wr * 64 + mf * 16 + kg * 4 + j;
                        float v = (row < M) ? acc[mf][nf][j] : 0.f;
                        cs += v; cq += v * v;
                    }
                cs += __shfl_xor(cs, 16); cs += __shfl_xor(cs, 32);
                cq += __shfl_xor(cq, 16); cq += __shfl_xor(cq, 32);
                if (kg == 0) { bns[wr][wc * (NF * 16) + nf * 16 + rf] = cs; bnq[wr][wc * (NF * 16) + nf * 16 + rf] = cq; }
            }
            __syncthreads();
            if (t < NF * 32) {
                atomicAdd(&gsum[n0 + t], bns[0][t] + bns[1][t]);
                atomicAdd(&gsq[n0 + t],  bnq[0][t] + bnq[1][t]);
            }
        }
    }
}

// ================= decode: logits[e] = dot64( bn(h[a]), bn(h[b]) ); BN finalize in-block =================
__global__ __launch_bounds__(256) void k_decode(const ushort* __restrict__ h,
                                                const float* __restrict__ bsum, const float* __restrict__ bsq,
                                                const float* __restrict__ bg, const float* __restrict__ bb,
                                                float invN,
                                                const int* __restrict__ pos, const int* __restrict__ neg,
                                                int Pp, int Pn, float* __restrict__ out) {
    __shared__ float scl[64], shl[64];
    int t = threadIdx.x;
    if (t < 64) {
        float m = bsum[t] * invN;
        float var = bsq[t] * invN - m * m;
        float sc = bg[t] * rsqrtf(var + 1e-5f);
        scl[t] = sc; shl[t] = bb[t] - m * sc;
    }
    __syncthreads();
    int gid = blockIdx.x * 16 + (t >> 4);
    int l = t & 15;
    int P = Pp + Pn;
    if (gid >= P) return;
    int a, b;
    if (gid < Pp) { a = pos[gid]; b = pos[Pp + gid]; }
    else          { int e = gid - Pp; a = neg[e]; b = neg[Pn + e]; }
    const uint2* hu = reinterpret_cast<const uint2*>(h);
    uint2 ua = hu[(size_t)a * 16 + l];
    uint2 ub = hu[(size_t)b * 16 + l];
    int f = l * 4;
    float s0 = scl[f], s1 = scl[f + 1], s2 = scl[f + 2], s3 = scl[f + 3];
    float t0 = shl[f], t1 = shl[f + 1], t2 = shl[f + 2], t3 = shl[f + 3];
    float a0 = bl(ua.x) * s0 + t0, a1 = bh(ua.x) * s1 + t1, a2 = bl(ua.y) * s2 + t2, a3 = bh(ua.y) * s3 + t3;
    float b0 = bl(ub.x) * s0 + t0, b1 = bh(ub.x) * s1 + t1, b2 = bl(ub.y) * s2 + t2, b3 = bh(ub.y) * s3 + t3;
    float d = a0 * b0 + a1 * b1 + a2 * b2 + a3 * b3;
    d += __shfl_xor(d, 1);
    d += __shfl_xor(d, 2);
    d += __shfl_xor(d, 4);
    d += __shfl_xor(d, 8);
    if (l == 0) out[gid] = d;
}

// ================= launch =================
extern "C" void kernel_launch(void* const* d_in, const int* in_sizes, int n_in,
                              void* d_out, int out_size, void* d_ws, size_t ws_size,
                              hipStream_t stream) {
    const float* x   = (const float*)d_in[0];
    const int*   ei  = (const int*)d_in[1];
    const int*   pe  = (const int*)d_in[2];
    const int*   ne  = (const int*)d_in[3];
    const float* W1  = (const float*)d_in[4];
    const float* g1  = (const float*)d_in[6];
    const float* be1 = (const float*)d_in[7];
    const float* W2  = (const float*)d_in[8];
    const float* g2  = (const float*)d_in[10];
    const float* be2 = (const float*)d_in[11];
    const float* W3  = (const float*)d_in[12];
    const float* g3  = (const float*)d_in[14];
    const float* be3 = (const float*)d_in[15];
    float* out = (float*)d_out;

    const int N  = in_sizes[0] / 128;
    const int E  = in_sizes[1] / 2;
    const int Pp = in_sizes[2] / 2;
    const int Pn = in_sizes[3] / 2;
    const float invN = 1.0f / (float)N;

    char* ws = (char*)d_ws;
    auto carve = [&](size_t bytes) -> char* {
        char* p = ws;
        ws += (bytes + 255) & ~(size_t)255;
        return p;
    };
    // zero zone: gh[256] + sums1[256]+sq1[256]+sums2[128]+sq2[128]+sums3[64]+sq3[64]
    char*  zz     = carve(256 * 4 + 896 * 4);
    int*   gh     = (int*)zz;
    float* sums1  = (float*)(zz + 1024);
    float* sq1    = sums1 + 256;
    float* sums2  = sq1 + 256;
    float* sq2    = sums2 + 128;
    float* sums3  = sq2 + 128;
    float* sq3    = sums3 + 64;
    size_t zz_bytes = 1024 + 896 * 4;

    int*    boff   = (int*)carve(257 * 4);
    int*    bcur   = (int*)carve(256 * 4);
    int*    rowptr = (int*)carve((size_t)(N + 1) * 4);
    float*  dinv   = (float*)carve((size_t)N * 4);
    int*    srcs   = (int*)carve((size_t)E * 4);
    uint*   pairs  = (uint*)carve((size_t)E * 4);
    ushort* Wt1    = (ushort*)carve(128 * 256 * 2);
    ushort* Wt2    = (ushort*)carve(256 * 128 * 2);
    ushort* Wt3    = (ushort*)carve(128 * 64 * 2);
    ushort* b1     = (ushort*)carve((size_t)N * 128 * 2);   // xb -> gemm2 out -> gemm3 out
    ushort* b2     = (ushort*)carve((size_t)N * 128 * 2);   // agg outs
    ushort* b3     = (ushort*)carve((size_t)N * 256 * 2);   // gemm1 out (h1 raw)

    const int* e_src = ei;
    const int* e_dst = ei + E;
    const int NBUCK = (N + (1 << BSHIFT) - 1) >> BSHIFT;

    hipMemsetAsync(zz, 0, zz_bytes, stream);

    // ---- CSR build: binned 2-level counting sort ----
    k_bhist<<<2048, 256, 0, stream>>>(e_dst, gh, E);
    k_bscan<<<1, 256, 0, stream>>>(gh, boff, bcur);
    k_bscatter<<<(E + SCHUNK - 1) / SCHUNK, 256, 0, stream>>>(e_src, e_dst, bcur, pairs, E);
    k_bfine<<<NBUCK, 256, 0, stream>>>(pairs, boff, rowptr, srcs, dinv, N, E);

    // ---- conversions ----
    {
        size_t n4 = (size_t)N * 128 / 4;
        k_convx<<<(int)((n4 + 255) / 256), 256, 0, stream>>>(x, b1, n4);
        k_convW<<<288, 256, 0, stream>>>(W1, W2, W3, Wt1, Wt2, Wt3);
    }

    const int mblk = (N + 127) / 128;
    const int agg128 = (N + 15) / 16;     // 4 nodes/wave * 4 waves
    const int agg64  = (N + 31) / 32;     // 8 nodes/wave * 4 waves

    // ---- Layer 1: agg(x) -> GEMM1 (2 n-passes, +stats) ----
    k_agg<128><<<agg128, 256, 0, stream>>>(b1, b2, rowptr, srcs, dinv, N);
    k_mfma<128, 4, 2, false, true><<<mblk, 256, 0, stream>>>(b2, Wt1, b3, N, 256,
        nullptr, nullptr, nullptr, nullptr, invN, sums1, sq1);

    // ---- Layer 2: GEMM2 (bn1+sig in staging) -> agg -> stats ----
    k_mfma<256, 4, 1, true, false><<<mblk, 256, 0, stream>>>(b3, Wt2, b1, N, 128,
        sums1, sq1, g1, be1, invN, nullptr, nullptr);
    k_agg<128><<<agg128, 256, 0, stream>>>(b1, b2, rowptr, srcs, dinv, N);
    k_bnstats<128><<<512, 256, 0, stream>>>(b2, sums2, sq2, N);

    // ---- Layer 3: GEMM3 (bn2+sig in staging) -> agg -> stats ----
    k_mfma<128, 2, 1, true, false><<<mblk, 256, 0, stream>>>(b2, Wt3, b1, N, 64,
        sums2, sq2, g2, be2, invN, nullptr, nullptr);
    k_agg<64><<<agg64, 256, 0, stream>>>(b1, b2, rowptr, srcs, dinv, N);
    k_bnstats<64><<<512, 256, 0, stream>>>(b2, sums3, sq3, N);

    // ---- decode (bn3 finalized + applied in-block) ----
    k_decode<<<(Pp + Pn + 15) / 16, 256, 0, stream>>>(b2, sums3, sq3, g3, be3, invN,
                                                      pe, ne, Pp, Pn, out);
}

// Round 7
// 544.427 us; speedup vs baseline: 1.0354x; 1.0354x over previous
//
#include <hip/hip_runtime.h>
#include <hip/hip_bf16.h>
#include <stddef.h>

// GCN link predictor: 3x (GCNConv -> BN -> [sigmoid]) then edge dot decode.
//  - CSR by dst via 2-level binned counting sort (write-coalesced, packed pairs).
//  - bf16 activations; MFMA 16x16x32 GEMMs, PURE (no fused transform):
//    A staged via global_load_lds (width 16) into linear LDS with pre-swizzled
//    global source (XOR involution) so ds_read_b128 fragments are conflict-free.
//    K=128: whole panel resident (2x16KB, one barrier). K=256: double-buffered
//    BK=64 pipeline (stage next before compute, 1 barrier/step). B direct-global.
//  - BN apply+sigmoid: standalone k_apply, per-thread fixed feature octet in regs.
//  - BN stats: GEMM1 epilogue (layer1); streaming k_bnstats after agg2/agg3.
//  - Biases cancel under training-mode BN -> skipped.  Assumes N <= 131072.

#define WAVE 64
#define BSHIFT 9                    // 512 nodes per coarse bucket
#define SCHUNK 4096                 // edges per bscatter block

typedef __attribute__((ext_vector_type(8))) short short8;
typedef __attribute__((ext_vector_type(4))) float f32x4;

__device__ __forceinline__ float bl(uint g) { return __uint_as_float(g << 16); }
__device__ __forceinline__ float bh(uint g) { return __uint_as_float(g & 0xffff0000u); }
__device__ __forceinline__ ushort f2b(float f) {           // round-to-nearest-even
    uint u = __float_as_uint(f);
    return (ushort)((u + 0x7fffu + ((u >> 16) & 1u)) >> 16);
}
__device__ __forceinline__ uint pack2(float lo, float hi) {
    return (uint)f2b(lo) | ((uint)f2b(hi) << 16);
}

// async global->LDS, 16B per lane; lds base must be wave-uniform (HW adds lane*16)
__device__ __forceinline__ void gload16(const ushort* g, ushort* l) {
    __builtin_amdgcn_global_load_lds(
        (const __attribute__((address_space(1))) uint*)g,
        (__attribute__((address_space(3))) uint*)l, 16, 0, 0);
}

// ================= binned counting sort (CSR build) =================
__global__ __launch_bounds__(256) void k_bhist(const int* __restrict__ dst, int* __restrict__ gh, int E) {
    __shared__ int lh[256];
    lh[threadIdx.x] = 0; __syncthreads();
    int i = blockIdx.x * 256 + threadIdx.x, stride = gridDim.x * 256;
    for (; i < E; i += stride) atomicAdd(&lh[dst[i] >> BSHIFT], 1);
    __syncthreads();
    int v = lh[threadIdx.x];
    if (v) atomicAdd(&gh[threadIdx.x], v);
}

__global__ void k_bscan(const int* __restrict__ gh, int* __restrict__ boff, int* __restrict__ bcur) {
    __shared__ int ls[256];
    int t = threadIdx.x;
    int v = gh[t];
    ls[t] = v; __syncthreads();
    for (int off = 1; off < 256; off <<= 1) {
        int x = (t >= off) ? ls[t - off] : 0;
        __syncthreads();
        ls[t] += x;
        __syncthreads();
    }
    int excl = ls[t] - v;
    boff[t] = excl; bcur[t] = excl;
    if (t == 255) boff[256] = ls[255];
}

// pairs packed: (dst & 511) << 17 | src   (src < 2^17, dloc < 2^9)
__global__ __launch_bounds__(256) void k_bscatter(const int* __restrict__ src, const int* __restrict__ dst,
                                                  int* __restrict__ gcur, uint* __restrict__ pairs, int E) {
    __shared__ int lh[256];
    int t = threadIdx.x;
    int base = blockIdx.x * SCHUNK;
    lh[t] = 0; __syncthreads();
    int rs[16], rd[16];
    #pragma unroll
    for (int i = 0; i < 16; ++i) {
        int idx = base + i * 256 + t;
        if (idx < E) { rs[i] = src[idx]; rd[i] = dst[idx]; atomicAdd(&lh[rd[i] >> BSHIFT], 1); }
        else rd[i] = -1;
    }
    __syncthreads();
    int cnt_b = lh[t];
    int b0 = cnt_b ? atomicAdd(&gcur[t], cnt_b) : 0;
    lh[t] = b0;
    __syncthreads();
    #pragma unroll
    for (int i = 0; i < 16; ++i) {
        if (rd[i] >= 0) {
            int p = atomicAdd(&lh[rd[i] >> BSHIFT], 1);
            pairs[p] = ((uint)(rd[i] & 511) << 17) | (uint)rs[i];
        }
    }
}

// per-bucket: fine counting sort; also emits rowptr + dinv
__global__ __launch_bounds__(256) void k_bfine(const uint* __restrict__ pairs, const int* __restrict__ boff,
                                               int* __restrict__ rowptr, int* __restrict__ srcs,
                                               float* __restrict__ dinv, int N, int E) {
    __shared__ int lcnt[512];
    __shared__ int ls[256];
    int b = blockIdx.x, t = threadIdx.x;
    int d0 = b << BSHIFT;
    int e0 = boff[b], e1 = boff[b + 1];
    lcnt[t] = 0; lcnt[t + 256] = 0;
    __syncthreads();
    for (int e = e0 + t; e < e1; e += 256)
        atomicAdd(&lcnt[pairs[e] >> 17], 1);
    __syncthreads();
    int c0 = lcnt[2 * t], c1 = lcnt[2 * t + 1];
    ls[t] = c0 + c1;
    __syncthreads();
    for (int off = 1; off < 256; off <<= 1) {
        int x = (t >= off) ? ls[t - off] : 0;
        __syncthreads();
        ls[t] += x;
        __syncthreads();
    }
    int excl = ls[t] - (c0 + c1);
    int s0 = excl, s1 = excl + c0;
    int d = d0 + 2 * t;
    if (d < N)     { rowptr[d] = e0 + s0;     dinv[d] = rsqrtf((float)(c0 + 1)); }
    if (d + 1 < N) { rowptr[d + 1] = e0 + s1; dinv[d + 1] = rsqrtf((float)(c1 + 1)); }
    if (b == 0 && t == 0) rowptr[N] = E;
    lcnt[2 * t] = s0; lcnt[2 * t + 1] = s1;
    __syncthreads();
    for (int e = e0 + t; e < e1; e += 256) {
        uint p = pairs[e];
        int pos = atomicAdd(&lcnt[p >> 17], 1);
        srcs[e0 + pos] = (int)(p & 0x1FFFFu);
    }
}

// ================= conversions =================
__global__ void k_convx(const float* __restrict__ in, ushort* __restrict__ out, size_t n4) {
    size_t i = (size_t)blockIdx.x * blockDim.x + threadIdx.x;
    if (i >= n4) return;
    float4 v = reinterpret_cast<const float4*>(in)[i];
    uint2 o;
    o.x = pack2(v.x, v.y);
    o.y = pack2(v.z, v.w);
    reinterpret_cast<uint2*>(out)[i] = o;
}

// all three weights transposed+converted in one launch: Wt[n*K+k] = bf16(W[k*N+n])
__global__ void k_convW(const float* __restrict__ W1, const float* __restrict__ W2,
                        const float* __restrict__ W3, ushort* __restrict__ Wt1,
                        ushort* __restrict__ Wt2, ushort* __restrict__ Wt3) {
    int i = blockIdx.x * blockDim.x + threadIdx.x;
    const float* W; ushort* Wt; int K, Nn, j;
    if (i < 32768)      { W = W1; Wt = Wt1; K = 128; Nn = 256; j = i; }
    else if (i < 65536) { W = W2; Wt = Wt2; K = 256; Nn = 128; j = i - 32768; }
    else if (i < 73728) { W = W3; Wt = Wt3; K = 128; Nn = 64;  j = i - 65536; }
    else return;
    int k = j / Nn, n = j % Nn;
    Wt[(size_t)n * K + k] = f2b(W[k * Nn + n]);
}

// ================= aggregation: out[i] = dinv[i]*( sum_e dinv[s]*in[s] + dinv[i]*in[i] ) =================
template<int F>
__global__ __launch_bounds__(256) void k_agg(const ushort* __restrict__ in, ushort* __restrict__ out,
                                             const int* __restrict__ rowptr, const int* __restrict__ srcs,
                                             const float* __restrict__ dinv, int N) {
    constexpr int L = (F * 2) / 16;          // lanes per node (uint4 = 16B each)
    int wv = threadIdx.x >> 6, lane = threadIdx.x & 63;
    int node = (blockIdx.x * 4 + wv) * (64 / L) + lane / L;
    int sl = lane % L;
    if (node >= N) return;
    const uint4* inq = reinterpret_cast<const uint4*>(in);
    float di = dinv[node];
    float acc[8];
    {
        uint4 v = inq[(size_t)node * L + sl];
        acc[0] = di * bl(v.x); acc[1] = di * bh(v.x);
        acc[2] = di * bl(v.y); acc[3] = di * bh(v.y);
        acc[4] = di * bl(v.z); acc[5] = di * bh(v.z);
        acc[6] = di * bl(v.w); acc[7] = di * bh(v.w);
    }
    int e = rowptr[node], e1 = rowptr[node + 1];
    for (; e + 3 < e1; e += 4) {
        int s0 = srcs[e], s1 = srcs[e + 1], s2 = srcs[e + 2], s3 = srcs[e + 3];
        float d0 = dinv[s0], d1 = dinv[s1], d2 = dinv[s2], d3 = dinv[s3];
        uint4 v0 = inq[(size_t)s0 * L + sl];
        uint4 v1 = inq[(size_t)s1 * L + sl];
        uint4 v2 = inq[(size_t)s2 * L + sl];
        uint4 v3 = inq[(size_t)s3 * L + sl];
        acc[0] += d0 * bl(v0.x) + d1 * bl(v1.x) + d2 * bl(v2.x) + d3 * bl(v3.x);
        acc[1] += d0 * bh(v0.x) + d1 * bh(v1.x) + d2 * bh(v2.x) + d3 * bh(v3.x);
        acc[2] += d0 * bl(v0.y) + d1 * bl(v1.y) + d2 * bl(v2.y) + d3 * bl(v3.y);
        acc[3] += d0 * bh(v0.y) + d1 * bh(v1.y) + d2 * bh(v2.y) + d3 * bh(v3.y);
        acc[4] += d0 * bl(v0.z) + d1 * bl(v1.z) + d2 * bl(v2.z) + d3 * bl(v3.z);
        acc[5] += d0 * bh(v0.z) + d1 * bh(v1.z) + d2 * bh(v2.z) + d3 * bh(v3.z);
        acc[6] += d0 * bl(v0.w) + d1 * bl(v1.w) + d2 * bl(v2.w) + d3 * bl(v3.w);
        acc[7] += d0 * bh(v0.w) + d1 * bh(v1.w) + d2 * bh(v2.w) + d3 * bh(v3.w);
    }
    for (; e < e1; ++e) {
        int s0 = srcs[e];
        float d0 = dinv[s0];
        uint4 v0 = inq[(size_t)s0 * L + sl];
        acc[0] += d0 * bl(v0.x); acc[1] += d0 * bh(v0.x);
        acc[2] += d0 * bl(v0.y); acc[3] += d0 * bh(v0.y);
        acc[4] += d0 * bl(v0.z); acc[5] += d0 * bh(v0.z);
        acc[6] += d0 * bl(v0.w); acc[7] += d0 * bh(v0.w);
    }
    uint4 o;
    o.x = pack2(acc[0] * di, acc[1] * di);
    o.y = pack2(acc[2] * di, acc[3] * di);
    o.z = pack2(acc[4] * di, acc[5] * di);
    o.w = pack2(acc[6] * di, acc[7] * di);
    reinterpret_cast<uint4*>(out)[(size_t)node * L + sl] = o;
}

// ================= vectorized BN stats (streaming, bf16 uint4 loads) =================
template<int F>
__global__ __launch_bounds__(256) void k_bnstats(const ushort* __restrict__ h, float* __restrict__ gsum,
                                                 float* __restrict__ gsq, int N) {
    constexpr int C = F / 8;                 // uint4 chunks per row (16 or 8)
    constexpr int RPW = 64 / C;              // rows per wave per step
    __shared__ float ls[4][16][16];          // [wave][chunk][0..7 sum, 8..15 sq]
    int wv = threadIdx.x >> 6, lane = threadIdx.x & 63;
    int fidx = lane % C, rsub = lane / C;
    int row = (blockIdx.x * 4 + wv) * RPW + rsub;
    int rstride = gridDim.x * 4 * RPW;
    const uint4* hq = reinterpret_cast<const uint4*>(h);
    float s[8] = {}, q[8] = {};
    for (int r = row; r < N; r += rstride) {
        uint4 v = hq[(size_t)r * C + fidx];
        float x;
        x = bl(v.x); s[0] += x; q[0] += x * x;
        x = bh(v.x); s[1] += x; q[1] += x * x;
        x = bl(v.y); s[2] += x; q[2] += x * x;
        x = bh(v.y); s[3] += x; q[3] += x * x;
        x = bl(v.z); s[4] += x; q[4] += x * x;
        x = bh(v.z); s[5] += x; q[5] += x * x;
        x = bl(v.w); s[6] += x; q[6] += x * x;
        x = bh(v.w); s[7] += x; q[7] += x * x;
    }
    #pragma unroll
    for (int m = C; m < 64; m <<= 1) {
        #pragma unroll
        for (int j = 0; j < 8; ++j) { s[j] += __shfl_xor(s[j], m); q[j] += __shfl_xor(q[j], m); }
    }
    if (lane < C) {
        #pragma unroll
        for (int j = 0; j < 8; ++j) { ls[wv][lane][j] = s[j]; ls[wv][lane][8 + j] = q[j]; }
    }
    __syncthreads();
    int t = threadIdx.x;
    if (t < F) {
        int ch = t / 8, j = t % 8;
        float S = 0.f, Q = 0.f;
        #pragma unroll
        for (int w = 0; w < 4; ++w) { S += ls[w][ch][j]; Q += ls[w][ch][8 + j]; }
        atomicAdd(&gsum[t], S); atomicAdd(&gsq[t], Q);
    }
}

// ================= BN apply + sigmoid (standalone, in-place, regs-only scale/shift) =================
// requires gridDim.x*256 % (F/8) == 0 so each thread's feature octet is fixed
template<int F>
__global__ __launch_bounds__(256) void k_apply(ushort* __restrict__ h,
                                               const float* __restrict__ bsum, const float* __restrict__ bsq,
                                               const float* __restrict__ bg, const float* __restrict__ bb,
                                               float invN, long NT) {
    constexpr int CPR = F / 8;
    int tid = blockIdx.x * 256 + threadIdx.x;
    int fb = (tid % CPR) * 8;
    float sc[8], sh[8];
    #pragma unroll
    for (int j = 0; j < 8; ++j) {
        float m = bsum[fb + j] * invN;
        float var = bsq[fb + j] * invN - m * m;
        float s = bg[fb + j] * rsqrtf(var + 1e-5f);
        sc[j] = s; sh[j] = bb[fb + j] - m * s;
    }
    uint4* hq = reinterpret_cast<uint4*>(h);
    long stride = (long)gridDim.x * 256;
    for (long i = tid; i < NT; i += stride) {
        uint4 v = hq[i];
        float x[8];
        x[0] = bl(v.x); x[1] = bh(v.x); x[2] = bl(v.y); x[3] = bh(v.y);
        x[4] = bl(v.z); x[5] = bh(v.z); x[6] = bl(v.w); x[7] = bh(v.w);
        #pragma unroll
        for (int j = 0; j < 8; ++j) {
            float y = x[j] * sc[j] + sh[j];
            x[j] = 1.f / (1.f + __expf(-y));
        }
        v.x = pack2(x[0], x[1]); v.y = pack2(x[2], x[3]);
        v.z = pack2(x[4], x[5]); v.w = pack2(x[6], x[7]);
        hq[i] = v;
    }
}

// ================= MFMA bf16 GEMM (pure): C[M, NPASS*NF*32] = A[M,K] @ Wt^T =================
// BM=128, 4 waves (2x2); wave tile 64 x NF*16. A staged via global_load_lds into
// linear LDS with pre-swizzled global source. K=128: both 16KB bufs resident,
// single barrier, NPASS passes. K=256: double-buffered BK=64 pipeline.
template<int K, int NF, int NPASS, bool STATS>
__global__ __launch_bounds__(256) void k_gemm(const ushort* __restrict__ A, const ushort* __restrict__ Wt,
                                              ushort* __restrict__ C, int M, int Nout,
                                              float* __restrict__ gsum, float* __restrict__ gsq) {
    constexpr int S = K / 64;                 // K-steps (2 or 4)
    constexpr int KS = K / 32;                // 32-wide slices
    __shared__ ushort Alds[2][128 * 64];      // 2 x 16KB
    int m0 = blockIdx.x * 128;
    int t = threadIdx.x;
    int w = t >> 6, lane = t & 63;
    int wr = w >> 1, wc = w & 1;
    int rf = lane & 15, kg = lane >> 4;

    // stage one BK=64 step into buf: 1024 chunks of 16B; wave-op = 64 chunks.
    // linear LDS dest chunk cb+l; global source chunk pre-swizzled (XOR involution).
    auto stage = [&](int buf, int step) {
        #pragma unroll
        for (int i = 0; i < 4; ++i) {
            int cb = (i * 4 + w) * 64;               // wave-uniform chunk base
            int chunk = cb + lane;
            int r = chunk >> 3, cs = chunk & 7;
            int c = cs ^ (r & 7);
            int gr = m0 + r; if (gr >= M) gr = M - 1;
            gload16(A + (size_t)gr * K + step * 64 + c * 8, &Alds[buf][cb * 8]);
        }
    };

    for (int pass = 0; pass < NPASS; ++pass) {
        int n0 = pass * NF * 32;
        const ushort* bp[NF];
        #pragma unroll
        for (int nf = 0; nf < NF; ++nf)
            bp[nf] = Wt + (size_t)(n0 + wc * (NF * 16) + nf * 16 + rf) * K + kg * 8;

        f32x4 acc[4][NF];
        #pragma unroll
        for (int mf = 0; mf < 4; ++mf)
            #pragma unroll
            for (int nf = 0; nf < NF; ++nf)
                acc[mf][nf] = (f32x4){0.f, 0.f, 0.f, 0.f};

        if (pass == 0) {
            stage(0, 0);
            if constexpr (S == 2) stage(1, 1);       // whole K resident
            __syncthreads();
        }

        short8 bcur[NF];
        #pragma unroll
        for (int nf = 0; nf < NF; ++nf)
            bcur[nf] = *reinterpret_cast<const short8*>(bp[nf]);

        for (int s = 0; s < S; ++s) {
            if constexpr (S > 2) {
                if (s + 1 < S && pass == 0) stage((s + 1) & 1, s + 1);
            }
            #pragma unroll
            for (int ksl = 0; ksl < 2; ++ksl) {
                int gs = s * 2 + ksl;
                short8 bnxt[NF];
                if (gs + 1 < KS) {
                    #pragma unroll
                    for (int nf = 0; nf < NF; ++nf)
                        bnxt[nf] = *reinterpret_cast<const short8*>(bp[nf] + (gs + 1) * 32);
                }
                short8 a[4];
                #pragma unroll
                for (int mf = 0; mf < 4; ++mf) {
                    int R = wr * 64 + mf * 16 + rf;
                    int idx = R * 8 + ((ksl * 4 + kg) ^ (R & 7));
                    a[mf] = *reinterpret_cast<const short8*>(&Alds[s & 1][idx * 8]);
                }
                #pragma unroll
                for (int mf = 0; mf < 4; ++mf)
                    #pragma unroll
                    for (int nf = 0; nf < NF; ++nf)
                        acc[mf][nf] = __builtin_amdgcn_mfma_f32_16x16x32_bf16(a[mf], bcur[nf], acc[mf][nf], 0, 0, 0);
                if (gs + 1 < KS) {
                    #pragma unroll
                    for (int nf = 0; nf < NF; ++nf) bcur[nf] = bnxt[nf];
                }
            }
            if constexpr (S > 2) __syncthreads();    // next-step buf ready; prev reads done
        }

        #pragma unroll
        for (int mf = 0; mf < 4; ++mf)
            #pragma unroll
            for (int nf = 0; nf < NF; ++nf) {
                int col = n0 + wc * (NF * 16) + nf * 16 + rf;
                #pragma unroll
                for (int j = 0; j < 4; ++j) {
                    int row = m0 + wr * 64 + mf * 16 + kg * 4 + j;
                    if (row < M) C[(size_t)row * Nout + col] = f2b(acc[mf][nf][j]);
                }
            }

        if constexpr (STATS) {
            __shared__ float bns[2][NF * 32], bnq[2][NF * 32];
            __syncthreads();                          // protect bns reuse across passes
            #pragma unroll
            for (int nf = 0; nf < NF; ++nf) {
                float cs = 0.f, cq = 0.f;
                #pragma unroll
                for (int mf = 0; mf < 4; ++mf)
                    #pragma unroll
                    for (int j = 0; j < 4; ++j) {
                        int row = m0 + wr * 64 + mf * 16 + kg * 4 + j;
                        float v = (row < M) ? acc[mf][nf][j] : 0.f;
                        cs += v; cq += v * v;
                    }
                cs += __shfl_xor(cs, 16); cs += __shfl_xor(cs, 32);
                cq += __shfl_xor(cq, 16); cq += __shfl_xor(cq, 32);
                if (kg == 0) { bns[wr][wc * (NF * 16) + nf * 16 + rf] = cs; bnq[wr][wc * (NF * 16) + nf * 16 + rf] = cq; }
            }
            __syncthreads();
            if (t < NF * 32) {
                atomicAdd(&gsum[n0 + t], bns[0][t] + bns[1][t]);
                atomicAdd(&gsq[n0 + t],  bnq[0][t] + bnq[1][t]);
            }
        }
    }
}

// ================= decode: logits[e] = dot64( bn(h[a]), bn(h[b]) ); BN finalize in-block =================
__global__ __launch_bounds__(256) void k_decode(const ushort* __restrict__ h,
                                                const float* __restrict__ bsum, const float* __restrict__ bsq,
                                                const float* __restrict__ bg, const float* __restrict__ bb,
                                                float invN,
                                                const int* __restrict__ pos, const int* __restrict__ neg,
                                                int Pp, int Pn, float* __restrict__ out) {
    __shared__ float scl[64], shl[64];
    int t = threadIdx.x;
    if (t < 64) {
        float m = bsum[t] * invN;
        float var = bsq[t] * invN - m * m;
        float sc = bg[t] * rsqrtf(var + 1e-5f);
        scl[t] = sc; shl[t] = bb[t] - m * sc;
    }
    __syncthreads();
    int gid = blockIdx.x * 16 + (t >> 4);
    int l = t & 15;
    int P = Pp + Pn;
    if (gid >= P) return;
    int a, b;
    if (gid < Pp) { a = pos[gid]; b = pos[Pp + gid]; }
    else          { int e = gid - Pp; a = neg[e]; b = neg[Pn + e]; }
    const uint2* hu = reinterpret_cast<const uint2*>(h);
    uint2 ua = hu[(size_t)a * 16 + l];
    uint2 ub = hu[(size_t)b * 16 + l];
    int f = l * 4;
    float s0 = scl[f], s1 = scl[f + 1], s2 = scl[f + 2], s3 = scl[f + 3];
    float t0 = shl[f], t1 = shl[f + 1], t2 = shl[f + 2], t3 = shl[f + 3];
    float a0 = bl(ua.x) * s0 + t0, a1 = bh(ua.x) * s1 + t1, a2 = bl(ua.y) * s2 + t2, a3 = bh(ua.y) * s3 + t3;
    float b0 = bl(ub.x) * s0 + t0, b1 = bh(ub.x) * s1 + t1, b2 = bl(ub.y) * s2 + t2, b3 = bh(ub.y) * s3 + t3;
    float d = a0 * b0 + a1 * b1 + a2 * b2 + a3 * b3;
    d += __shfl_xor(d, 1);
    d += __shfl_xor(d, 2);
    d += __shfl_xor(d, 4);
    d += __shfl_xor(d, 8);
    if (l == 0) out[gid] = d;
}

// ================= launch =================
extern "C" void kernel_launch(void* const* d_in, const int* in_sizes, int n_in,
                              void* d_out, int out_size, void* d_ws, size_t ws_size,
                              hipStream_t stream) {
    const float* x   = (const float*)d_in[0];
    const int*   ei  = (const int*)d_in[1];
    const int*   pe  = (const int*)d_in[2];
    const int*   ne  = (const int*)d_in[3];
    const float* W1  = (const float*)d_in[4];
    const float* g1  = (const float*)d_in[6];
    const float* be1 = (const float*)d_in[7];
    const float* W2  = (const float*)d_in[8];
    const float* g2  = (const float*)d_in[10];
    const float* be2 = (const float*)d_in[11];
    const float* W3  = (const float*)d_in[12];
    const float* g3  = (const float*)d_in[14];
    const float* be3 = (const float*)d_in[15];
    float* out = (float*)d_out;

    const int N  = in_sizes[0] / 128;
    const int E  = in_sizes[1] / 2;
    const int Pp = in_sizes[2] / 2;
    const int Pn = in_sizes[3] / 2;
    const float invN = 1.0f / (float)N;

    char* ws = (char*)d_ws;
    auto carve = [&](size_t bytes) -> char* {
        char* p = ws;
        ws += (bytes + 255) & ~(size_t)255;
        return p;
    };
    // zero zone: gh[256] + sums1[256]+sq1[256]+sums2[128]+sq2[128]+sums3[64]+sq3[64]
    char*  zz     = carve(256 * 4 + 896 * 4);
    int*   gh     = (int*)zz;
    float* sums1  = (float*)(zz + 1024);
    float* sq1    = sums1 + 256;
    float* sums2  = sq1 + 256;
    float* sq2    = sums2 + 128;
    float* sums3  = sq2 + 128;
    float* sq3    = sums3 + 64;
    size_t zz_bytes = 1024 + 896 * 4;

    int*    boff   = (int*)carve(257 * 4);
    int*    bcur   = (int*)carve(256 * 4);
    int*    rowptr = (int*)carve((size_t)(N + 1) * 4);
    float*  dinv   = (float*)carve((size_t)N * 4);
    int*    srcs   = (int*)carve((size_t)E * 4);
    uint*   pairs  = (uint*)carve((size_t)E * 4);
    ushort* Wt1    = (ushort*)carve(128 * 256 * 2);
    ushort* Wt2    = (ushort*)carve(256 * 128 * 2);
    ushort* Wt3    = (ushort*)carve(128 * 64 * 2);
    ushort* b1     = (ushort*)carve((size_t)N * 128 * 2);   // xb -> gemm2 out -> gemm3 out
    ushort* b2     = (ushort*)carve((size_t)N * 128 * 2);   // agg outs
    ushort* b3     = (ushort*)carve((size_t)N * 256 * 2);   // gemm1 out (h1 raw -> act1)

    const int* e_src = ei;
    const int* e_dst = ei + E;
    const int NBUCK = (N + (1 << BSHIFT) - 1) >> BSHIFT;

    hipMemsetAsync(zz, 0, zz_bytes, stream);

    // ---- CSR build: binned 2-level counting sort ----
    k_bhist<<<2048, 256, 0, stream>>>(e_dst, gh, E);
    k_bscan<<<1, 256, 0, stream>>>(gh, boff, bcur);
    k_bscatter<<<(E + SCHUNK - 1) / SCHUNK, 256, 0, stream>>>(e_src, e_dst, bcur, pairs, E);
    k_bfine<<<NBUCK, 256, 0, stream>>>(pairs, boff, rowptr, srcs, dinv, N, E);

    // ---- conversions ----
    {
        size_t n4 = (size_t)N * 128 / 4;
        k_convx<<<(int)((n4 + 255) / 256), 256, 0, stream>>>(x, b1, n4);
        k_convW<<<288, 256, 0, stream>>>(W1, W2, W3, Wt1, Wt2, Wt3);
    }

    const int mblk = (N + 127) / 128;
    const int agg128 = (N + 15) / 16;     // 4 nodes/wave * 4 waves
    const int agg64  = (N + 31) / 32;     // 8 nodes/wave * 4 waves

    // ---- Layer 1: agg(x) -> GEMM1 (pure, 2 n-passes, +stats) -> apply1 ----
    k_agg<128><<<agg128, 256, 0, stream>>>(b1, b2, rowptr, srcs, dinv, N);
    k_gemm<128, 4, 2, true><<<mblk, 256, 0, stream>>>(b2, Wt1, b3, N, 256, sums1, sq1);
    k_apply<256><<<2048, 256, 0, stream>>>(b3, sums1, sq1, g1, be1, invN, (long)N * 32);

    // ---- Layer 2: GEMM2 (pure, dbuf K=256) -> agg -> stats -> apply2 ----
    k_gemm<256, 4, 1, false><<<mblk, 256, 0, stream>>>(b3, Wt2, b1, N, 128, nullptr, nullptr);
    k_agg<128><<<agg128, 256, 0, stream>>>(b1, b2, rowptr, srcs, dinv, N);
    k_bnstats<128><<<512, 256, 0, stream>>>(b2, sums2, sq2, N);
    k_apply<128><<<2048, 256, 0, stream>>>(b2, sums2, sq2, g2, be2, invN, (long)N * 16);

    // ---- Layer 3: GEMM3 (pure) -> agg -> stats ----
    k_gemm<128, 2, 1, false><<<mblk, 256, 0, stream>>>(b2, Wt3, b1, N, 64, nullptr, nullptr);
    k_agg<64><<<agg64, 256, 0, stream>>>(b1, b2, rowptr, srcs, dinv, N);
    k_bnstats<64><<<512, 256, 0, stream>>>(b2, sums3, sq3, N);

    // ---- decode (bn3 finalized + applied in-block) ----
    k_decode<<<(Pp + Pn + 15) / 16, 256, 0, stream>>>(b2, sums3, sq3, g3, be3, invN,
                                                      pe, ne, Pp, Pn, out);
}

// Round 8
// 536.627 us; speedup vs baseline: 1.0505x; 1.0145x over previous
//
#include <hip/hip_runtime.h>
#include <hip/hip_bf16.h>
#include <stddef.h>

// GCN link predictor: 3x (GCNConv -> BN -> [sigmoid]) then edge dot decode.
//  - CSR by dst via 2-level binned counting sort (write-coalesced, packed pairs).
//  - bf16 activations; MFMA 16x16x32 GEMMs, pure compute, A staged via
//    global_load_lds (width 16) into linear LDS with pre-swizzled global source.
//  - Agg inputs PRE-SCALED by dinv at their producers (convx / GEMM epilogues):
//    h[i] = dinv[i]*(sum_s xs[s] + xs[i]) -> agg edge loop is a single row-gather
//    stream (no per-edge dinv loads), 8-edge unrolled for MLP.
//  - BN apply+sigmoid: standalone k_apply, per-thread fixed feature octet in regs.
//  - BN stats: GEMM1 epilogue (layer1); streaming k_bnstats after agg2/agg3.
//  - Biases cancel under training-mode BN -> skipped.  Assumes N <= 131072.

#define WAVE 64
#define BSHIFT 9                    // 512 nodes per coarse bucket
#define SCHUNK 4096                 // edges per bscatter block

typedef __attribute__((ext_vector_type(8))) short short8;
typedef __attribute__((ext_vector_type(4))) float f32x4;

__device__ __forceinline__ float bl(uint g) { return __uint_as_float(g << 16); }
__device__ __forceinline__ float bh(uint g) { return __uint_as_float(g & 0xffff0000u); }
__device__ __forceinline__ ushort f2b(float f) {           // round-to-nearest-even
    uint u = __float_as_uint(f);
    return (ushort)((u + 0x7fffu + ((u >> 16) & 1u)) >> 16);
}
__device__ __forceinline__ uint pack2(float lo, float hi) {
    return (uint)f2b(lo) | ((uint)f2b(hi) << 16);
}

// async global->LDS, 16B per lane; lds base must be wave-uniform (HW adds lane*16)
__device__ __forceinline__ void gload16(const ushort* g, ushort* l) {
    __builtin_amdgcn_global_load_lds(
        (const __attribute__((address_space(1))) uint*)g,
        (__attribute__((address_space(3))) uint*)l, 16, 0, 0);
}

// ================= binned counting sort (CSR build) =================
__global__ __launch_bounds__(256) void k_bhist(const int* __restrict__ dst, int* __restrict__ gh, int E) {
    __shared__ int lh[256];
    lh[threadIdx.x] = 0; __syncthreads();
    int i = blockIdx.x * 256 + threadIdx.x, stride = gridDim.x * 256;
    for (; i < E; i += stride) atomicAdd(&lh[dst[i] >> BSHIFT], 1);
    __syncthreads();
    int v = lh[threadIdx.x];
    if (v) atomicAdd(&gh[threadIdx.x], v);
}

__global__ void k_bscan(const int* __restrict__ gh, int* __restrict__ boff, int* __restrict__ bcur) {
    __shared__ int ls[256];
    int t = threadIdx.x;
    int v = gh[t];
    ls[t] = v; __syncthreads();
    for (int off = 1; off < 256; off <<= 1) {
        int x = (t >= off) ? ls[t - off] : 0;
        __syncthreads();
        ls[t] += x;
        __syncthreads();
    }
    int excl = ls[t] - v;
    boff[t] = excl; bcur[t] = excl;
    if (t == 255) boff[256] = ls[255];
}

// pairs packed: (dst & 511) << 17 | src   (src < 2^17, dloc < 2^9)
__global__ __launch_bounds__(256) void k_bscatter(const int* __restrict__ src, const int* __restrict__ dst,
                                                  int* __restrict__ gcur, uint* __restrict__ pairs, int E) {
    __shared__ int lh[256];
    int t = threadIdx.x;
    int base = blockIdx.x * SCHUNK;
    lh[t] = 0; __syncthreads();
    int rs[16], rd[16];
    #pragma unroll
    for (int i = 0; i < 16; ++i) {
        int idx = base + i * 256 + t;
        if (idx < E) { rs[i] = src[idx]; rd[i] = dst[idx]; atomicAdd(&lh[rd[i] >> BSHIFT], 1); }
        else rd[i] = -1;
    }
    __syncthreads();
    int cnt_b = lh[t];
    int b0 = cnt_b ? atomicAdd(&gcur[t], cnt_b) : 0;
    lh[t] = b0;
    __syncthreads();
    #pragma unroll
    for (int i = 0; i < 16; ++i) {
        if (rd[i] >= 0) {
            int p = atomicAdd(&lh[rd[i] >> BSHIFT], 1);
            pairs[p] = ((uint)(rd[i] & 511) << 17) | (uint)rs[i];
        }
    }
}

// per-bucket: fine counting sort; also emits rowptr + dinv
__global__ __launch_bounds__(256) void k_bfine(const uint* __restrict__ pairs, const int* __restrict__ boff,
                                               int* __restrict__ rowptr, int* __restrict__ srcs,
                                               float* __restrict__ dinv, int N, int E) {
    __shared__ int lcnt[512];
    __shared__ int ls[256];
    int b = blockIdx.x, t = threadIdx.x;
    int d0 = b << BSHIFT;
    int e0 = boff[b], e1 = boff[b + 1];
    lcnt[t] = 0; lcnt[t + 256] = 0;
    __syncthreads();
    for (int e = e0 + t; e < e1; e += 256)
        atomicAdd(&lcnt[pairs[e] >> 17], 1);
    __syncthreads();
    int c0 = lcnt[2 * t], c1 = lcnt[2 * t + 1];
    ls[t] = c0 + c1;
    __syncthreads();
    for (int off = 1; off < 256; off <<= 1) {
        int x = (t >= off) ? ls[t - off] : 0;
        __syncthreads();
        ls[t] += x;
        __syncthreads();
    }
    int excl = ls[t] - (c0 + c1);
    int s0 = excl, s1 = excl + c0;
    int d = d0 + 2 * t;
    if (d < N)     { rowptr[d] = e0 + s0;     dinv[d] = rsqrtf((float)(c0 + 1)); }
    if (d + 1 < N) { rowptr[d + 1] = e0 + s1; dinv[d + 1] = rsqrtf((float)(c1 + 1)); }
    if (b == 0 && t == 0) rowptr[N] = E;
    lcnt[2 * t] = s0; lcnt[2 * t + 1] = s1;
    __syncthreads();
    for (int e = e0 + t; e < e1; e += 256) {
        uint p = pairs[e];
        int pos = atomicAdd(&lcnt[p >> 17], 1);
        srcs[e0 + pos] = (int)(p & 0x1FFFFu);
    }
}

// ================= conversions (merged): W transposes + x pre-scaled by dinv =================
__global__ void k_conv(const float* __restrict__ W1, const float* __restrict__ W2,
                       const float* __restrict__ W3, ushort* __restrict__ Wt1,
                       ushort* __restrict__ Wt2, ushort* __restrict__ Wt3,
                       const float* __restrict__ x, const float* __restrict__ dinv,
                       ushort* __restrict__ xs, size_t n4) {
    size_t i = (size_t)blockIdx.x * 256 + threadIdx.x;
    if (i < 73728) {
        const float* W; ushort* Wt; int K, Nn; size_t j;
        if (i < 32768)      { W = W1; Wt = Wt1; K = 128; Nn = 256; j = i; }
        else if (i < 65536) { W = W2; Wt = Wt2; K = 256; Nn = 128; j = i - 32768; }
        else                { W = W3; Wt = Wt3; K = 128; Nn = 64;  j = i - 65536; }
        int k = (int)(j / Nn), n = (int)(j % Nn);
        Wt[(size_t)n * K + k] = f2b(W[(size_t)k * Nn + n]);
        return;
    }
    size_t j = i - 73728;
    if (j >= n4) return;
    float d = dinv[j / 32];                     // 32 float4 per 128-wide row
    float4 v = reinterpret_cast<const float4*>(x)[j];
    uint2 o;
    o.x = pack2(d * v.x, d * v.y);
    o.y = pack2(d * v.z, d * v.w);
    reinterpret_cast<uint2*>(xs)[j] = o;
}

// ================= aggregation: h[i] = dinv[i]*( sum_e xs[s] + xs[i] )  (xs pre-scaled) =================
template<int F>
__global__ __launch_bounds__(256) void k_agg(const ushort* __restrict__ in, ushort* __restrict__ out,
                                             const int* __restrict__ rowptr, const int* __restrict__ srcs,
                                             const float* __restrict__ dinv, int N) {
    constexpr int L = (F * 2) / 16;          // lanes per node (uint4 = 16B each)
    int wv = threadIdx.x >> 6, lane = threadIdx.x & 63;
    int node = (blockIdx.x * 4 + wv) * (64 / L) + lane / L;
    int sl = lane % L;
    if (node >= N) return;
    const uint4* inq = reinterpret_cast<const uint4*>(in);
    float di = dinv[node];
    float acc[8];
    {
        uint4 v = inq[(size_t)node * L + sl];    // self: + xs[i]
        acc[0] = bl(v.x); acc[1] = bh(v.x);
        acc[2] = bl(v.y); acc[3] = bh(v.y);
        acc[4] = bl(v.z); acc[5] = bh(v.z);
        acc[6] = bl(v.w); acc[7] = bh(v.w);
    }
    int e = rowptr[node], e1 = rowptr[node + 1];
    for (; e + 7 < e1; e += 8) {
        int s[8];
        #pragma unroll
        for (int i = 0; i < 8; ++i) s[i] = srcs[e + i];
        uint4 v[8];
        #pragma unroll
        for (int i = 0; i < 8; ++i) v[i] = inq[(size_t)s[i] * L + sl];
        #pragma unroll
        for (int i = 0; i < 8; ++i) {
            acc[0] += bl(v[i].x); acc[1] += bh(v[i].x);
            acc[2] += bl(v[i].y); acc[3] += bh(v[i].y);
            acc[4] += bl(v[i].z); acc[5] += bh(v[i].z);
            acc[6] += bl(v[i].w); acc[7] += bh(v[i].w);
        }
    }
    for (; e + 3 < e1; e += 4) {
        int s[4];
        #pragma unroll
        for (int i = 0; i < 4; ++i) s[i] = srcs[e + i];
        uint4 v[4];
        #pragma unroll
        for (int i = 0; i < 4; ++i) v[i] = inq[(size_t)s[i] * L + sl];
        #pragma unroll
        for (int i = 0; i < 4; ++i) {
            acc[0] += bl(v[i].x); acc[1] += bh(v[i].x);
            acc[2] += bl(v[i].y); acc[3] += bh(v[i].y);
            acc[4] += bl(v[i].z); acc[5] += bh(v[i].z);
            acc[6] += bl(v[i].w); acc[7] += bh(v[i].w);
        }
    }
    for (; e < e1; ++e) {
        uint4 v0 = inq[(size_t)srcs[e] * L + sl];
        acc[0] += bl(v0.x); acc[1] += bh(v0.x);
        acc[2] += bl(v0.y); acc[3] += bh(v0.y);
        acc[4] += bl(v0.z); acc[5] += bh(v0.z);
        acc[6] += bl(v0.w); acc[7] += bh(v0.w);
    }
    uint4 o;
    o.x = pack2(acc[0] * di, acc[1] * di);
    o.y = pack2(acc[2] * di, acc[3] * di);
    o.z = pack2(acc[4] * di, acc[5] * di);
    o.w = pack2(acc[6] * di, acc[7] * di);
    reinterpret_cast<uint4*>(out)[(size_t)node * L + sl] = o;
}

// ================= vectorized BN stats (streaming, bf16 uint4 loads) =================
template<int F>
__global__ __launch_bounds__(256) void k_bnstats(const ushort* __restrict__ h, float* __restrict__ gsum,
                                                 float* __restrict__ gsq, int N) {
    constexpr int C = F / 8;                 // uint4 chunks per row (16 or 8)
    constexpr int RPW = 64 / C;              // rows per wave per step
    __shared__ float ls[4][16][16];          // [wave][chunk][0..7 sum, 8..15 sq]
    int wv = threadIdx.x >> 6, lane = threadIdx.x & 63;
    int fidx = lane % C, rsub = lane / C;
    int row = (blockIdx.x * 4 + wv) * RPW + rsub;
    int rstride = gridDim.x * 4 * RPW;
    const uint4* hq = reinterpret_cast<const uint4*>(h);
    float s[8] = {}, q[8] = {};
    for (int r = row; r < N; r += rstride) {
        uint4 v = hq[(size_t)r * C + fidx];
        float x;
        x = bl(v.x); s[0] += x; q[0] += x * x;
        x = bh(v.x); s[1] += x; q[1] += x * x;
        x = bl(v.y); s[2] += x; q[2] += x * x;
        x = bh(v.y); s[3] += x; q[3] += x * x;
        x = bl(v.z); s[4] += x; q[4] += x * x;
        x = bh(v.z); s[5] += x; q[5] += x * x;
        x = bl(v.w); s[6] += x; q[6] += x * x;
        x = bh(v.w); s[7] += x; q[7] += x * x;
    }
    #pragma unroll
    for (int m = C; m < 64; m <<= 1) {
        #pragma unroll
        for (int j = 0; j < 8; ++j) { s[j] += __shfl_xor(s[j], m); q[j] += __shfl_xor(q[j], m); }
    }
    if (lane < C) {
        #pragma unroll
        for (int j = 0; j < 8; ++j) { ls[wv][lane][j] = s[j]; ls[wv][lane][8 + j] = q[j]; }
    }
    __syncthreads();
    int t = threadIdx.x;
    if (t < F) {
        int ch = t / 8, j = t % 8;
        float S = 0.f, Q = 0.f;
        #pragma unroll
        for (int w = 0; w < 4; ++w) { S += ls[w][ch][j]; Q += ls[w][ch][8 + j]; }
        atomicAdd(&gsum[t], S); atomicAdd(&gsq[t], Q);
    }
}

// ================= BN apply + sigmoid (standalone, in-place, regs-only scale/shift) =================
// requires gridDim.x*256 % (F/8) == 0 so each thread's feature octet is fixed
template<int F>
__global__ __launch_bounds__(256) void k_apply(ushort* __restrict__ h,
                                               const float* __restrict__ bsum, const float* __restrict__ bsq,
                                               const float* __restrict__ bg, const float* __restrict__ bb,
                                               float invN, long NT) {
    constexpr int CPR = F / 8;
    int tid = blockIdx.x * 256 + threadIdx.x;
    int fb = (tid % CPR) * 8;
    float sc[8], sh[8];
    #pragma unroll
    for (int j = 0; j < 8; ++j) {
        float m = bsum[fb + j] * invN;
        float var = bsq[fb + j] * invN - m * m;
        float s = bg[fb + j] * rsqrtf(var + 1e-5f);
        sc[j] = s; sh[j] = bb[fb + j] - m * s;
    }
    uint4* hq = reinterpret_cast<uint4*>(h);
    long stride = (long)gridDim.x * 256;
    for (long i = tid; i < NT; i += stride) {
        uint4 v = hq[i];
        float x[8];
        x[0] = bl(v.x); x[1] = bh(v.x); x[2] = bl(v.y); x[3] = bh(v.y);
        x[4] = bl(v.z); x[5] = bh(v.z); x[6] = bl(v.w); x[7] = bh(v.w);
        #pragma unroll
        for (int j = 0; j < 8; ++j) {
            float y = x[j] * sc[j] + sh[j];
            x[j] = 1.f / (1.f + __expf(-y));
        }
        v.x = pack2(x[0], x[1]); v.y = pack2(x[2], x[3]);
        v.z = pack2(x[4], x[5]); v.w = pack2(x[6], x[7]);
        hq[i] = v;
    }
}

// ================= MFMA bf16 GEMM (pure): C[M, NPASS*NF*32] = A[M,K] @ Wt^T =================
// BM=128, 4 waves (2x2); wave tile 64 x NF*16. A staged via global_load_lds into
// linear LDS with pre-swizzled global source. K=128: both 16KB bufs resident,
// single barrier, NPASS passes. K=256: double-buffered BK=64 pipeline.
// PRESCALE: epilogue multiplies C rows by dinv[row] (pre-scaling for next agg).
template<int K, int NF, int NPASS, bool STATS, bool PRESCALE>
__global__ __launch_bounds__(256) void k_gemm(const ushort* __restrict__ A, const ushort* __restrict__ Wt,
                                              ushort* __restrict__ C, int M, int Nout,
                                              const float* __restrict__ dinv,
                                              float* __restrict__ gsum, float* __restrict__ gsq) {
    constexpr int S = K / 64;                 // K-steps (2 or 4)
    constexpr int KS = K / 32;                // 32-wide slices
    __shared__ ushort Alds[2][128 * 64];      // 2 x 16KB
    int m0 = blockIdx.x * 128;
    int t = threadIdx.x;
    int w = t >> 6, lane = t & 63;
    int wr = w >> 1, wc = w & 1;
    int rf = lane & 15, kg = lane >> 4;

    auto stage = [&](int buf, int step) {
        #pragma unroll
        for (int i = 0; i < 4; ++i) {
            int cb = (i * 4 + w) * 64;               // wave-uniform chunk base
            int chunk = cb + lane;
            int r = chunk >> 3, cs = chunk & 7;
            int c = cs ^ (r & 7);
            int gr = m0 + r; if (gr >= M) gr = M - 1;
            gload16(A + (size_t)gr * K + step * 64 + c * 8, &Alds[buf][cb * 8]);
        }
    };

    float dreg[4][4];
    if constexpr (PRESCALE) {
        #pragma unroll
        for (int mf = 0; mf < 4; ++mf)
            #pragma unroll
            for (int j = 0; j < 4; ++j) {
                int row = m0 + wr * 64 + mf * 16 + kg * 4 + j;
                dreg[mf][j] = (row < M) ? dinv[row] : 0.f;
            }
    }

    for (int pass = 0; pass < NPASS; ++pass) {
        int n0 = pass * NF * 32;
        const ushort* bp[NF];
        #pragma unroll
        for (int nf = 0; nf < NF; ++nf)
            bp[nf] = Wt + (size_t)(n0 + wc * (NF * 16) + nf * 16 + rf) * K + kg * 8;

        f32x4 acc[4][NF];
        #pragma unroll
        for (int mf = 0; mf < 4; ++mf)
            #pragma unroll
            for (int nf = 0; nf < NF; ++nf)
                acc[mf][nf] = (f32x4){0.f, 0.f, 0.f, 0.f};

        if (pass == 0) {
            stage(0, 0);
            if constexpr (S == 2) stage(1, 1);       // whole K resident
            __syncthreads();
        }

        short8 bcur[NF];
        #pragma unroll
        for (int nf = 0; nf < NF; ++nf)
            bcur[nf] = *reinterpret_cast<const short8*>(bp[nf]);

        for (int s = 0; s < S; ++s) {
            if constexpr (S > 2) {
                if (s + 1 < S && pass == 0) stage((s + 1) & 1, s + 1);
            }
            #pragma unroll
            for (int ksl = 0; ksl < 2; ++ksl) {
                int gs = s * 2 + ksl;
                short8 bnxt[NF];
                if (gs + 1 < KS) {
                    #pragma unroll
                    for (int nf = 0; nf < NF; ++nf)
                        bnxt[nf] = *reinterpret_cast<const short8*>(bp[nf] + (gs + 1) * 32);
                }
                short8 a[4];
                #pragma unroll
                for (int mf = 0; mf < 4; ++mf) {
                    int R = wr * 64 + mf * 16 + rf;
                    int idx = R * 8 + ((ksl * 4 + kg) ^ (R & 7));
                    a[mf] = *reinterpret_cast<const short8*>(&Alds[s & 1][idx * 8]);
                }
                #pragma unroll
                for (int mf = 0; mf < 4; ++mf)
                    #pragma unroll
                    for (int nf = 0; nf < NF; ++nf)
                        acc[mf][nf] = __builtin_amdgcn_mfma_f32_16x16x32_bf16(a[mf], bcur[nf], acc[mf][nf], 0, 0, 0);
                if (gs + 1 < KS) {
                    #pragma unroll
                    for (int nf = 0; nf < NF; ++nf) bcur[nf] = bnxt[nf];
                }
            }
            if constexpr (S > 2) __syncthreads();    // next-step buf ready; prev reads done
        }

        #pragma unroll
        for (int mf = 0; mf < 4; ++mf)
            #pragma unroll
            for (int nf = 0; nf < NF; ++nf) {
                int col = n0 + wc * (NF * 16) + nf * 16 + rf;
                #pragma unroll
                for (int j = 0; j < 4; ++j) {
                    int row = m0 + wr * 64 + mf * 16 + kg * 4 + j;
                    float v = acc[mf][nf][j];
                    if constexpr (PRESCALE) v *= dreg[mf][j];
                    if (row < M) C[(size_t)row * Nout + col] = f2b(v);
                }
            }

        if constexpr (STATS) {
            __shared__ float bns[2][NF * 32], bnq[2][NF * 32];
            __syncthreads();                          // protect bns reuse across passes
            #pragma unroll
            for (int nf = 0; nf < NF; ++nf) {
                float cs = 0.f, cq = 0.f;
                #pragma unroll
                for (int mf = 0; mf < 4; ++mf)
                    #pragma unroll
                    for (int j = 0; j < 4; ++j) {
                        int row = m0 + wr * 64 + mf * 16 + kg * 4 + j;
                        float v = (row < M) ? acc[mf][nf][j] : 0.f;
                        cs += v; cq += v * v;
                    }
                cs += __shfl_xor(cs, 16); cs += __shfl_xor(cs, 32);
                cq += __shfl_xor(cq, 16); cq += __shfl_xor(cq, 32);
                if (kg == 0) { bns[wr][wc * (NF * 16) + nf * 16 + rf] = cs; bnq[wr][wc * (NF * 16) + nf * 16 + rf] = cq; }
            }
            __syncthreads();
            if (t < NF * 32) {
                atomicAdd(&gsum[n0 + t], bns[0][t] + bns[1][t]);
                atomicAdd(&gsq[n0 + t],  bnq[0][t] + bnq[1][t]);
            }
        }
    }
}

// ================= decode: logits[e] = dot64( bn(h[a]), bn(h[b]) ); BN finalize in-block =================
__global__ __launch_bounds__(256) void k_decode(const ushort* __restrict__ h,
                                                const float* __restrict__ bsum, const float* __restrict__ bsq,
                                                const float* __restrict__ bg, const float* __restrict__ bb,
                                                float invN,
                                                const int* __restrict__ pos, const int* __restrict__ neg,
                                                int Pp, int Pn, float* __restrict__ out) {
    __shared__ float scl[64], shl[64];
    int t = threadIdx.x;
    if (t < 64) {
        float m = bsum[t] * invN;
        float var = bsq[t] * invN - m * m;
        float sc = bg[t] * rsqrtf(var + 1e-5f);
        scl[t] = sc; shl[t] = bb[t] - m * sc;
    }
    __syncthreads();
    int gid = blockIdx.x * 16 + (t >> 4);
    int l = t & 15;
    int P = Pp + Pn;
    if (gid >= P) return;
    int a, b;
    if (gid < Pp) { a = pos[gid]; b = pos[Pp + gid]; }
    else          { int e = gid - Pp; a = neg[e]; b = neg[Pn + e]; }
    const uint2* hu = reinterpret_cast<const uint2*>(h);
    uint2 ua = hu[(size_t)a * 16 + l];
    uint2 ub = hu[(size_t)b * 16 + l];
    int f = l * 4;
    float s0 = scl[f], s1 = scl[f + 1], s2 = scl[f + 2], s3 = scl[f + 3];
    float t0 = shl[f], t1 = shl[f + 1], t2 = shl[f + 2], t3 = shl[f + 3];
    float a0 = bl(ua.x) * s0 + t0, a1 = bh(ua.x) * s1 + t1, a2 = bl(ua.y) * s2 + t2, a3 = bh(ua.y) * s3 + t3;
    float b0 = bl(ub.x) * s0 + t0, b1 = bh(ub.x) * s1 + t1, b2 = bl(ub.y) * s2 + t2, b3 = bh(ub.y) * s3 + t3;
    float d = a0 * b0 + a1 * b1 + a2 * b2 + a3 * b3;
    d += __shfl_xor(d, 1);
    d += __shfl_xor(d, 2);
    d += __shfl_xor(d, 4);
    d += __shfl_xor(d, 8);
    if (l == 0) out[gid] = d;
}

// ================= launch =================
extern "C" void kernel_launch(void* const* d_in, const int* in_sizes, int n_in,
                              void* d_out, int out_size, void* d_ws, size_t ws_size,
                              hipStream_t stream) {
    const float* x   = (const float*)d_in[0];
    const int*   ei  = (const int*)d_in[1];
    const int*   pe  = (const int*)d_in[2];
    const int*   ne  = (const int*)d_in[3];
    const float* W1  = (const float*)d_in[4];
    const float* g1  = (const float*)d_in[6];
    const float* be1 = (const float*)d_in[7];
    const float* W2  = (const float*)d_in[8];
    const float* g2  = (const float*)d_in[10];
    const float* be2 = (const float*)d_in[11];
    const float* W3  = (const float*)d_in[12];
    const float* g3  = (const float*)d_in[14];
    const float* be3 = (const float*)d_in[15];
    float* out = (float*)d_out;

    const int N  = in_sizes[0] / 128;
    const int E  = in_sizes[1] / 2;
    const int Pp = in_sizes[2] / 2;
    const int Pn = in_sizes[3] / 2;
    const float invN = 1.0f / (float)N;

    char* ws = (char*)d_ws;
    auto carve = [&](size_t bytes) -> char* {
        char* p = ws;
        ws += (bytes + 255) & ~(size_t)255;
        return p;
    };
    // zero zone: gh[256] + sums1[256]+sq1[256]+sums2[128]+sq2[128]+sums3[64]+sq3[64]
    char*  zz     = carve(256 * 4 + 896 * 4);
    int*   gh     = (int*)zz;
    float* sums1  = (float*)(zz + 1024);
    float* sq1    = sums1 + 256;
    float* sums2  = sq1 + 256;
    float* sq2    = sums2 + 128;
    float* sums3  = sq2 + 128;
    float* sq3    = sums3 + 64;
    size_t zz_bytes = 1024 + 896 * 4;

    int*    boff   = (int*)carve(257 * 4);
    int*    bcur   = (int*)carve(256 * 4);
    int*    rowptr = (int*)carve((size_t)(N + 1) * 4);
    float*  dinv   = (float*)carve((size_t)N * 4);
    int*    srcs   = (int*)carve((size_t)E * 4);
    uint*   pairs  = (uint*)carve((size_t)E * 4);
    ushort* Wt1    = (ushort*)carve(128 * 256 * 2);
    ushort* Wt2    = (ushort*)carve(256 * 128 * 2);
    ushort* Wt3    = (ushort*)carve(128 * 64 * 2);
    ushort* b1     = (ushort*)carve((size_t)N * 128 * 2);   // xs0 -> gemm2 out -> gemm3 out
    ushort* b2     = (ushort*)carve((size_t)N * 128 * 2);   // agg outs
    ushort* b3     = (ushort*)carve((size_t)N * 256 * 2);   // gemm1 out (h1 raw -> act1)

    const int* e_src = ei;
    const int* e_dst = ei + E;
    const int NBUCK = (N + (1 << BSHIFT) - 1) >> BSHIFT;

    hipMemsetAsync(zz, 0, zz_bytes, stream);

    // ---- CSR build: binned 2-level counting sort ----
    k_bhist<<<2048, 256, 0, stream>>>(e_dst, gh, E);
    k_bscan<<<1, 256, 0, stream>>>(gh, boff, bcur);
    k_bscatter<<<(E + SCHUNK - 1) / SCHUNK, 256, 0, stream>>>(e_src, e_dst, bcur, pairs, E);
    k_bfine<<<NBUCK, 256, 0, stream>>>(pairs, boff, rowptr, srcs, dinv, N, E);

    // ---- conversions (W transpose + x pre-scale) ----
    {
        size_t n4 = (size_t)N * 128 / 4;
        int blocks = (int)((73728 + n4 + 255) / 256);
        k_conv<<<blocks, 256, 0, stream>>>(W1, W2, W3, Wt1, Wt2, Wt3, x, dinv, b1, n4);
    }

    const int mblk = (N + 127) / 128;
    const int agg128 = (N + 15) / 16;     // 4 nodes/wave * 4 waves
    const int agg64  = (N + 31) / 32;     // 8 nodes/wave * 4 waves

    // ---- Layer 1: agg(xs0) -> GEMM1 (pure, 2 n-passes, +stats) -> apply1 ----
    k_agg<128><<<agg128, 256, 0, stream>>>(b1, b2, rowptr, srcs, dinv, N);
    k_gemm<128, 4, 2, true, false><<<mblk, 256, 0, stream>>>(b2, Wt1, b3, N, 256, nullptr, sums1, sq1);
    k_apply<256><<<2048, 256, 0, stream>>>(b3, sums1, sq1, g1, be1, invN, (long)N * 32);

    // ---- Layer 2: GEMM2 (dbuf K=256, prescale) -> agg -> stats -> apply2 ----
    k_gemm<256, 4, 1, false, true><<<mblk, 256, 0, stream>>>(b3, Wt2, b1, N, 128, dinv, nullptr, nullptr);
    k_agg<128><<<agg128, 256, 0, stream>>>(b1, b2, rowptr, srcs, dinv, N);
    k_bnstats<128><<<512, 256, 0, stream>>>(b2, sums2, sq2, N);
    k_apply<128><<<2048, 256, 0, stream>>>(b2, sums2, sq2, g2, be2, invN, (long)N * 16);

    // ---- Layer 3: GEMM3 (prescale) -> agg -> stats ----
    k_gemm<128, 2, 1, false, true><<<mblk, 256, 0, stream>>>(b2, Wt3, b1, N, 64, dinv, nullptr, nullptr);
    k_agg<64><<<agg64, 256, 0, stream>>>(b1, b2, rowptr, srcs, dinv, N);
    k_bnstats<64><<<512, 256, 0, stream>>>(b2, sums3, sq3, N);

    // ---- decode (bn3 finalized + applied in-block) ----
    k_decode<<<(Pp + Pn + 15) / 16, 256, 0, stream>>>(b2, sums3, sq3, g3, be3, invN,
                                                      pe, ne, Pp, Pn, out);
}